// Round 1
// baseline (229.620 us; speedup 1.0000x reference)
//
#include <hip/hip_runtime.h>
#include <math.h>

#define NB   32
#define SQ   1024
#define INF  128
#define OUTF 64
#define OHH  256

using bf16x8 = __attribute__((ext_vector_type(8))) __bf16;
using bf16x4 = __attribute__((ext_vector_type(4))) __bf16;
using f32x4  = __attribute__((ext_vector_type(4))) float;

// ---------------------------------------------------------------------------
// Kernel A: per 64-row tile of the flattened (N*S, INF) h matrix:
//   - build WM (head-mean of W) + w_f = W@a1, w_g = W@a2 in LDS
//   - fp32 GEMM: WhM = h @ WM  (64x64 tile, K=128)
//   - split WhM into bf16 hi/lo and store in MFMA-B fragment order:
//       element (n, J, T, lane, idx) = WhM[n][J*32 + (lane>>4)*8 + idx][T*16 + (lane&15)]
//       flat ushort addr = ((n*32+J)*4 + T)*512 + lane*8 + idx
//   - f = h@w_f, g = h@w_g
// ---------------------------------------------------------------------------
__global__ __launch_bounds__(256) void kA(
    const float* __restrict__ h, const float* __restrict__ W,
    const float* __restrict__ a, __bf16* __restrict__ whmH,
    __bf16* __restrict__ whmL, float* __restrict__ fo, float* __restrict__ go)
{
    __shared__ float WMl[INF][68];   // cols 0..63 = WM, 64 = w_f, 65 = w_g
    __shared__ float hT[INF][68];    // hT[k][r] transposed h tile (pad 68: 2-way max)
    __shared__ float al[2 * OHH];
    __shared__ float fgp[8][64];

    const int t  = threadIdx.x;
    const int R0 = blockIdx.x * 64;  // 64 rows, never straddles a batch (64|1024)

    // stage a (512 floats)
    al[t]       = a[t];
    al[t + 256] = a[t + 256];

    // WM[k][c] = mean over 4 heads
    for (int idx = t; idx < INF * OUTF; idx += 256) {
        int k = idx >> 6, c = idx & 63;
        const float* Wr = W + k * OHH + c;
        WMl[k][c] = 0.25f * (Wr[0] + Wr[64] + Wr[128] + Wr[192]);
    }

    // stage h tile transposed: thread (r = t>>2, kq = (t&3)*4)
    {
        const int r  = t >> 2;
        const int kq = (t & 3) << 2;
        const float* hrow = h + (size_t)(R0 + r) * INF;
        #pragma unroll
        for (int it = 0; it < 8; ++it) {
            int k0 = it * 16 + kq;
            float4 v = *(const float4*)(hrow + k0);
            hT[k0 + 0][r] = v.x; hT[k0 + 1][r] = v.y;
            hT[k0 + 2][r] = v.z; hT[k0 + 3][r] = v.w;
        }
    }
    __syncthreads();

    // w_f, w_g (threads 0..127, one W row each; W is L2-hot)
    if (t < INF) {
        const float4* Wr = (const float4*)(W + t * OHH);
        const float4* a1 = (const float4*)al;
        const float4* a2 = (const float4*)(al + OHH);
        float sf = 0.f, sg = 0.f;
        for (int q = 0; q < OHH / 4; ++q) {
            float4 wv = Wr[q], x1 = a1[q], x2 = a2[q];
            sf += wv.x * x1.x + wv.y * x1.y + wv.z * x1.z + wv.w * x1.w;
            sg += wv.x * x2.x + wv.y * x2.y + wv.z * x2.z + wv.w * x2.w;
        }
        WMl[t][64] = sf;
        WMl[t][65] = sg;
    }
    __syncthreads();

    // 64x64 fp32 tile GEMM, 4x4 microtile
    const int tx = t & 15, ty = t >> 4;
    const int c0 = tx << 2, r0 = ty << 2;
    float acc[4][4] = {};
    #pragma unroll 4
    for (int k = 0; k < INF; ++k) {
        f32x4 av = *(const f32x4*)&hT[k][r0];
        f32x4 bv = *(const f32x4*)&WMl[k][c0];
        #pragma unroll
        for (int i = 0; i < 4; ++i)
            #pragma unroll
            for (int j = 0; j < 4; ++j)
                acc[i][j] += av[i] * bv[j];
    }

    // split + store in B-fragment order (hi/lo bf16)
    {
        const int n    = R0 >> 10;
        const int J    = ((R0 & 1023) >> 5) + (ty >> 3);
        const int quad = (ty & 7) >> 1;
        const int idx0 = (ty & 1) << 2;
        const int T    = tx >> 2;
        #pragma unroll
        for (int jj = 0; jj < 4; ++jj) {
            const int cl   = ((tx & 3) << 2) + jj;
            const int lane = quad * 16 + cl;
            const size_t base =
                (((size_t)(n * 32 + J) * 4 + T) * 64 + lane) * 8 + idx0;
            bf16x4 hv, lv;
            #pragma unroll
            for (int i = 0; i < 4; ++i) {
                float p  = acc[i][jj];
                __bf16 hb = (__bf16)p;          // RTNE hi
                hv[i] = hb;
                lv[i] = (__bf16)(p - (float)hb); // exact residual -> bf16
            }
            *(bf16x4*)(whmH + base) = hv;
            *(bf16x4*)(whmL + base) = lv;
        }
    }

    // f,g: partial dot over k-quarters, then reduce
    {
        const int r = t & 63, grp = t >> 6;
        float sf = 0.f, sg = 0.f;
        for (int k = grp * 32; k < grp * 32 + 32; ++k) {
            float hv = hT[k][r];
            sf += hv * WMl[k][64];
            sg += hv * WMl[k][65];
        }
        fgp[grp][r]     = sf;
        fgp[4 + grp][r] = sg;
    }
    __syncthreads();
    if (t < 64) {
        fo[R0 + t] = fgp[0][t] + fgp[1][t] + fgp[2][t] + fgp[3][t];
    } else if (t < 128) {
        int r = t - 64;
        go[R0 + r] = fgp[4][r] + fgp[5][r] + fgp[6][r] + fgp[7][r];
    }
}

// ---------------------------------------------------------------------------
// Kernel C: per (batch n, 64-row i-tile): out = softmax_j(lrelu(f_i+g_j)) @ WhM
// via split-bf16 MFMA 16x16x32; l_i accumulated in-loop from exact fp32 p.
// Epilogue: scale by 1/l, ELU (x>0 ? x : expm1(x)).
// ---------------------------------------------------------------------------
__global__ __launch_bounds__(256) void kC(
    const __bf16* __restrict__ whmH, const __bf16* __restrict__ whmL,
    const float* __restrict__ fi, const float* __restrict__ gi,
    float* __restrict__ out)
{
    __shared__ float  gl[SQ];
    __shared__ float  fl[64];
    __shared__ __bf16 bfr[4096];   // 8 frags (4T hi, 4T lo) x 64 lanes x 8 = 8KB

    const int t     = threadIdx.x;
    const int lane  = t & 63;
    const int wid   = t >> 6;
    const int n     = blockIdx.x & 31;   // bx%8 == n%8 -> batch pinned to one XCD
    const int itile = blockIdx.x >> 5;
    const int i0    = itile * 64;

    // stage g (4KB) and f (64 rows)
    ((float4*)gl)[t] = ((const float4*)(gi + n * SQ))[t];
    if (t < 64) fl[t] = fi[n * SQ + i0 + t];
    __syncthreads();

    const float myf = fl[wid * 16 + (lane & 15)]; // A-frag row m = lane&15
    const int   kq  = lane >> 4;                  // A-frag k-quad

    const __bf16* srcH = whmH + (size_t)n * 65536;
    const __bf16* srcL = whmL + (size_t)n * 65536;

    f32x4 acc[4] = {};
    float lsum = 0.f;

    for (int J = 0; J < 32; ++J) {
        // stage 8KB of B-frags (already fragment-ordered in global)
        {
            const f32x4* sH = (const f32x4*)(srcH + (size_t)J * 2048);
            const f32x4* sL = (const f32x4*)(srcL + (size_t)J * 2048);
            f32x4* d = (f32x4*)bfr;
            d[t]       = sH[t];
            d[256 + t] = sL[t];
        }

        // A-frags: this lane's 8 j's: j = J*32 + kq*8 + idx
        float p[8];
        {
            const float4 g0 = *(const float4*)&gl[J * 32 + kq * 8];
            const float4 g1 = *(const float4*)&gl[J * 32 + kq * 8 + 4];
            float gs8[8] = {g0.x, g0.y, g0.z, g0.w, g1.x, g1.y, g1.z, g1.w};
            #pragma unroll
            for (int idx = 0; idx < 8; ++idx) {
                float e  = myf + gs8[idx];
                float lr = 0.55f * e + 0.45f * fabsf(e);  // leakyrelu(0.1)
                p[idx] = __expf(lr);                      // no max-sub needed (fp32 range)
            }
        }
        lsum += ((p[0] + p[1]) + (p[2] + p[3])) + ((p[4] + p[5]) + (p[6] + p[7]));

        bf16x8 ph, pl;
        #pragma unroll
        for (int idx = 0; idx < 8; ++idx) {
            __bf16 hb = (__bf16)p[idx];
            ph[idx] = hb;
            pl[idx] = (__bf16)(p[idx] - (float)hb);
        }

        __syncthreads();  // frags staged
        const bf16x8* fr = (const bf16x8*)bfr;
        #pragma unroll
        for (int T = 0; T < 4; ++T) {
            bf16x8 bh = fr[T * 64 + lane];
            bf16x8 bl = fr[(4 + T) * 64 + lane];
            acc[T] = __builtin_amdgcn_mfma_f32_16x16x32_bf16(ph, bh, acc[T], 0, 0, 0);
            acc[T] = __builtin_amdgcn_mfma_f32_16x16x32_bf16(pl, bh, acc[T], 0, 0, 0);
            acc[T] = __builtin_amdgcn_mfma_f32_16x16x32_bf16(ph, bl, acc[T], 0, 0, 0);
        }
        __syncthreads();  // before next stage overwrites bfr
    }

    // l reduction: row m = lane&15 lives in lanes {m, m+16, m+32, m+48}
    lsum += __shfl_xor(lsum, 16, 64);
    lsum += __shfl_xor(lsum, 32, 64);
    const float rv = 1.0f / lsum;  // 1/l for row (lane&15)

    const int rq = lane >> 4;
    float scs[4];
    #pragma unroll
    for (int r = 0; r < 4; ++r)
        scs[r] = __shfl(rv, rq * 4 + r, 64);  // C/D row = rq*4 + reg

    const int colbase = lane & 15;
    #pragma unroll
    for (int T = 0; T < 4; ++T) {
        #pragma unroll
        for (int r = 0; r < 4; ++r) {
            int   rr = rq * 4 + r;
            float v  = acc[T][r] * scs[r];
            v = v > 0.f ? v : expm1f(v);      // final ELU
            out[(size_t)(n * SQ + i0 + wid * 16 + rr) * OUTF + T * 16 + colbase] = v;
        }
    }
}

extern "C" void kernel_launch(void* const* d_in, const int* in_sizes, int n_in,
                              void* d_out, int out_size, void* d_ws, size_t ws_size,
                              hipStream_t stream) {
    const float* h = (const float*)d_in[0];
    // d_in[1] = adj : unused by the reference computation
    const float* W = (const float*)d_in[2];
    const float* a = (const float*)d_in[3];

    char* ws = (char*)d_ws;
    __bf16* whmH = (__bf16*)ws;                                   // 4 MB
    __bf16* whmL = (__bf16*)(ws + (size_t)4 * 1024 * 1024);       // 4 MB
    float*  fb   = (float*)(ws + (size_t)8 * 1024 * 1024);        // 128 KB
    float*  gb   = (float*)(ws + (size_t)8 * 1024 * 1024 + 131072);
    float*  outp = (float*)d_out;

    hipLaunchKernelGGL(kA, dim3(512), dim3(256), 0, stream, h, W, a, whmH, whmL, fb, gb);
    hipLaunchKernelGGL(kC, dim3(512), dim3(256), 0, stream, whmH, whmL, fb, gb, outp);
}

// Round 2
// 216.723 us; speedup vs baseline: 1.0595x; 1.0595x over previous
//
#include <hip/hip_runtime.h>
#include <math.h>

#define NB   32
#define SQ   1024
#define INF  128
#define OUTF 64
#define OHH  256

using bf16x8 = __attribute__((ext_vector_type(8))) __bf16;
using bf16x4 = __attribute__((ext_vector_type(4))) __bf16;
using f32x4  = __attribute__((ext_vector_type(4))) float;

// ---------------------------------------------------------------------------
// Kernel A: per 64-row tile of the flattened (N*S, INF) h matrix:
//   - build WM (head-mean of W) + w_f = W@a1, w_g = W@a2 in LDS
//   - fp32 GEMM: WhM = h @ WM  (64x64 tile, K=128)
//   - split WhM into bf16 hi/lo, store in MFMA-B fragment order:
//       flat addr = ((n*32+J)*4 + T)*512 + lane*8 + idx   (idx<8, lane<64)
//   - f = h@w_f, g = h@w_g
// ---------------------------------------------------------------------------
__global__ __launch_bounds__(256) void kA(
    const float* __restrict__ h, const float* __restrict__ W,
    const float* __restrict__ a, __bf16* __restrict__ whmH,
    __bf16* __restrict__ whmL, float* __restrict__ fo, float* __restrict__ go)
{
    __shared__ float WMl[INF][68];   // cols 0..63 = WM, 64 = w_f, 65 = w_g
    __shared__ float hT[INF][68];    // hT[k][r] transposed h tile (68: 16B-aligned rows)
    __shared__ float al[2 * OHH];
    __shared__ float fgp[8][64];

    const int t  = threadIdx.x;
    const int R0 = blockIdx.x * 64;  // 64 rows, never straddles a batch (64|1024)

    // stage a (512 floats)
    al[t]       = a[t];
    al[t + 256] = a[t + 256];

    // WM[k][c] = mean over 4 heads (wave-coalesced: 64 consecutive c per instr)
    for (int idx = t; idx < INF * OUTF; idx += 256) {
        int k = idx >> 6, c = idx & 63;
        const float* Wr = W + k * OHH + c;
        WMl[k][c] = 0.25f * (Wr[0] + Wr[64] + Wr[128] + Wr[192]);
    }

    // stage h tile transposed
    {
        const int r  = t >> 2;
        const int kq = (t & 3) << 2;
        const float* hrow = h + (size_t)(R0 + r) * INF;
        #pragma unroll
        for (int it = 0; it < 8; ++it) {
            int k0 = it * 16 + kq;
            float4 v = *(const float4*)(hrow + k0);
            hT[k0 + 0][r] = v.x; hT[k0 + 1][r] = v.y;
            hT[k0 + 2][r] = v.z; hT[k0 + 3][r] = v.w;
        }
    }
    __syncthreads();

    // w_f, w_g (threads 0..127, one W row each; W is L2-hot)
    if (t < INF) {
        const float4* Wr = (const float4*)(W + t * OHH);
        const float4* a1 = (const float4*)al;
        const float4* a2 = (const float4*)(al + OHH);
        float sf = 0.f, sg = 0.f;
        for (int q = 0; q < OHH / 4; ++q) {
            float4 wv = Wr[q], x1 = a1[q], x2 = a2[q];
            sf += wv.x * x1.x + wv.y * x1.y + wv.z * x1.z + wv.w * x1.w;
            sg += wv.x * x2.x + wv.y * x2.y + wv.z * x2.z + wv.w * x2.w;
        }
        WMl[t][64] = sf;
        WMl[t][65] = sg;
    }
    __syncthreads();

    // 64x64 fp32 tile GEMM, 4x4 microtile
    const int tx = t & 15, ty = t >> 4;
    const int c0 = tx << 2, r0 = ty << 2;
    float acc[4][4] = {};
    #pragma unroll 4
    for (int k = 0; k < INF; ++k) {
        f32x4 av = *(const f32x4*)&hT[k][r0];
        f32x4 bv = *(const f32x4*)&WMl[k][c0];
        #pragma unroll
        for (int i = 0; i < 4; ++i)
            #pragma unroll
            for (int j = 0; j < 4; ++j)
                acc[i][j] += av[i] * bv[j];
    }

    // split + store in B-fragment order (hi/lo bf16)
    {
        const int n    = R0 >> 10;
        const int J    = ((R0 & 1023) >> 5) + (ty >> 3);
        const int quad = (ty & 7) >> 1;
        const int idx0 = (ty & 1) << 2;
        const int T    = tx >> 2;
        #pragma unroll
        for (int jj = 0; jj < 4; ++jj) {
            const int cl   = ((tx & 3) << 2) + jj;
            const int lane = quad * 16 + cl;
            const size_t base =
                (((size_t)(n * 32 + J) * 4 + T) * 64 + lane) * 8 + idx0;
            bf16x4 hv, lv;
            #pragma unroll
            for (int i = 0; i < 4; ++i) {
                float p  = acc[i][jj];
                __bf16 hb = (__bf16)p;           // RTNE hi
                hv[i] = hb;
                lv[i] = (__bf16)(p - (float)hb); // exact residual -> bf16
            }
            *(bf16x4*)(whmH + base) = hv;
            *(bf16x4*)(whmL + base) = lv;
        }
    }

    // f,g: partial dot over k-quarters, then reduce
    {
        const int r = t & 63, grp = t >> 6;
        float sf = 0.f, sg = 0.f;
        for (int k = grp * 32; k < grp * 32 + 32; ++k) {
            float hv = hT[k][r];
            sf += hv * WMl[k][64];
            sg += hv * WMl[k][65];
        }
        fgp[grp][r]     = sf;
        fgp[4 + grp][r] = sg;
    }
    __syncthreads();
    if (t < 64) {
        fo[R0 + t] = fgp[0][t] + fgp[1][t] + fgp[2][t] + fgp[3][t];
    } else if (t < 128) {
        int r = t - 64;
        go[R0 + r] = fgp[4][r] + fgp[5][r] + fgp[6][r] + fgp[7][r];
    }
}

// ---------------------------------------------------------------------------
// Kernel C: per (batch n, 64-row i-tile): out = softmax_j(lrelu(f_i+g_j)) @ WhM
// split-bf16 MFMA 16x16x32. 3-deep async LDS ring: stage(J+2) issued right
// after barrier(J) via global_load_lds dwordx4 (wave-uniform base + lane*16),
// so each staged load has a full iteration in flight before its consuming
// barrier. One __syncthreads per J.
// ---------------------------------------------------------------------------
__global__ __launch_bounds__(256) void kC(
    const __bf16* __restrict__ whmH, const __bf16* __restrict__ whmL,
    const float* __restrict__ fi, const float* __restrict__ gi,
    float* __restrict__ out)
{
    __shared__ float  gl[SQ];
    __shared__ float  fl[64];
    __shared__ __bf16 bfr[3][4096];  // ring: 3 x (hi 4KB + lo 4KB)

    const int t     = threadIdx.x;
    const int lane  = t & 63;
    const int wid   = t >> 6;
    const int n     = blockIdx.x & 31;   // bx%8 == n%8 -> batch pinned per XCD
    const int itile = blockIdx.x >> 5;
    const int i0    = itile * 64;

    const char* gHb = (const char*)(whmH + (size_t)n * 65536) + wid * 1024 + lane * 16;
    const char* gLb = (const char*)(whmL + (size_t)n * 65536) + wid * 1024 + lane * 16;

    // async stage of buffer `buf` with chunk J (8KB: hi then lo)
    auto stage = [&](int J, int buf) {
        char* lH = (char*)&bfr[buf][0] + wid * 1024;          // wave-uniform base
        char* lL = (char*)&bfr[buf][2048] + wid * 1024;
        __builtin_amdgcn_global_load_lds(
            (const __attribute__((address_space(1))) unsigned int*)(gHb + (size_t)J * 4096),
            (__attribute__((address_space(3))) unsigned int*)lH, 16, 0, 0);
        __builtin_amdgcn_global_load_lds(
            (const __attribute__((address_space(1))) unsigned int*)(gLb + (size_t)J * 4096),
            (__attribute__((address_space(3))) unsigned int*)lL, 16, 0, 0);
    };

    // stage g (4KB) and f (64 rows)
    ((float4*)gl)[t] = ((const float4*)(gi + n * SQ))[t];
    if (t < 64) fl[t] = fi[n * SQ + i0 + t];

    stage(0, 0);
    stage(1, 1);
    __syncthreads();   // gl/fl visible (also drains prologue stages)

    const float myf = fl[wid * 16 + (lane & 15)]; // A-frag row m = lane&15
    const int   kq  = lane >> 4;                  // A-frag k-quad

    f32x4 acc[4] = {};
    float lsum = 0.f;

    for (int J = 0; J < 32; ++J) {
        // A-frags first (only reads gl/fl): overlaps other waves' MFMA
        float p[8];
        {
            const float4 g0 = *(const float4*)&gl[J * 32 + kq * 8];
            const float4 g1 = *(const float4*)&gl[J * 32 + kq * 8 + 4];
            float gs8[8] = {g0.x, g0.y, g0.z, g0.w, g1.x, g1.y, g1.z, g1.w};
            #pragma unroll
            for (int idx = 0; idx < 8; ++idx) {
                float e  = myf + gs8[idx];
                float lr = 0.55f * e + 0.45f * fabsf(e);  // leakyrelu(0.1)
                p[idx] = __expf(lr);                      // fp32 range safe, no max-sub
            }
        }
        lsum += ((p[0] + p[1]) + (p[2] + p[3])) + ((p[4] + p[5]) + (p[6] + p[7]));

        bf16x8 ph, pl;
        #pragma unroll
        for (int idx = 0; idx < 8; ++idx) {
            __bf16 hb = (__bf16)p[idx];
            ph[idx] = hb;
            pl[idx] = (__bf16)(p[idx] - (float)hb);
        }

        // barrier(J): all waves done MFMA(J-1) [ring slot (J+2)%3 free],
        // vmcnt drain completes stage(J) issued >=1 full iteration ago.
        __syncthreads();
        if (J + 2 < 32) stage(J + 2, (J + 2) % 3);   // in flight during MFMA(J)

        const bf16x8* fr = (const bf16x8*)&bfr[J % 3][0];
        #pragma unroll
        for (int T = 0; T < 4; ++T) {
            bf16x8 bh = fr[T * 64 + lane];
            bf16x8 bl = fr[(4 + T) * 64 + lane];
            acc[T] = __builtin_amdgcn_mfma_f32_16x16x32_bf16(ph, bh, acc[T], 0, 0, 0);
            acc[T] = __builtin_amdgcn_mfma_f32_16x16x32_bf16(pl, bh, acc[T], 0, 0, 0);
            acc[T] = __builtin_amdgcn_mfma_f32_16x16x32_bf16(ph, bl, acc[T], 0, 0, 0);
        }
    }

    // l reduction: row m = lane&15 lives in lanes {m, m+16, m+32, m+48}
    lsum += __shfl_xor(lsum, 16, 64);
    lsum += __shfl_xor(lsum, 32, 64);
    const float rv = 1.0f / lsum;  // 1/l for row (lane&15)

    const int rq = lane >> 4;
    float scs[4];
    #pragma unroll
    for (int r = 0; r < 4; ++r)
        scs[r] = __shfl(rv, rq * 4 + r, 64);  // C/D row = rq*4 + reg

    const int colbase = lane & 15;
    #pragma unroll
    for (int T = 0; T < 4; ++T) {
        #pragma unroll
        for (int r = 0; r < 4; ++r) {
            int   rr = rq * 4 + r;
            float v  = acc[T][r] * scs[r];
            v = v > 0.f ? v : expm1f(v);      // final ELU
            out[(size_t)(n * SQ + i0 + wid * 16 + rr) * OUTF + T * 16 + colbase] = v;
        }
    }
}

extern "C" void kernel_launch(void* const* d_in, const int* in_sizes, int n_in,
                              void* d_out, int out_size, void* d_ws, size_t ws_size,
                              hipStream_t stream) {
    const float* h = (const float*)d_in[0];
    // d_in[1] = adj : unused by the reference computation
    const float* W = (const float*)d_in[2];
    const float* a = (const float*)d_in[3];

    char* ws = (char*)d_ws;
    __bf16* whmH = (__bf16*)ws;                                   // 4 MB
    __bf16* whmL = (__bf16*)(ws + (size_t)4 * 1024 * 1024);       // 4 MB
    float*  fb   = (float*)(ws + (size_t)8 * 1024 * 1024);        // 128 KB
    float*  gb   = (float*)(ws + (size_t)8 * 1024 * 1024 + 131072);
    float*  outp = (float*)d_out;

    hipLaunchKernelGGL(kA, dim3(512), dim3(256), 0, stream, h, W, a, whmH, whmL, fb, gb);
    hipLaunchKernelGGL(kC, dim3(512), dim3(256), 0, stream, whmH, whmL, fb, gb, outp);
}

// Round 4
// 215.497 us; speedup vs baseline: 1.0655x; 1.0057x over previous
//
#include <hip/hip_runtime.h>
#include <math.h>

#define SQ    1024
#define INF   128
#define OUTF  64
#define OHH   256
#define LOG2E 1.44269504088896f

using bf16x8 = __attribute__((ext_vector_type(8))) __bf16;
using bf16x4 = __attribute__((ext_vector_type(4))) __bf16;
using f32x4  = __attribute__((ext_vector_type(4))) float;
using u16x8  = __attribute__((ext_vector_type(8))) unsigned short;

#if __has_builtin(__builtin_amdgcn_exp2f)
#define EXP2F(x) __builtin_amdgcn_exp2f(x)
#else
#define EXP2F(x) __expf((x) * 0.6931471805599453f)
#endif

// ---------------------------------------------------------------------------
// Kernel A (MFMA version): per 64-row tile of flattened (N*S, INF) h:
//   - WM (head-mean of W) built in LDS directly in MFMA-B-frag layout,
//     split hi (RNE) / lo (residual).  SIZE: 128x64 = 8192 elems per buffer!
//   - h loaded from global in A-frag order (row = lane&15, k strip = lane>>4),
//     trunc-split into bf16 hi/lo
//   - WhM = h @ WM via 3-term split MFMA (Ah*Bh + Al*Bh + Ah*Bl)
//   - f' = (h@w_f)*log2e, g' = (h@w_g)*log2e via in-register fp32 dots + shfl
//   - WhM split hi/lo, stored in B-frag order for kC:
//       flat = ((n*32+J)*4 + T)*512 + lane'*8 + idx'
// ---------------------------------------------------------------------------
__global__ __launch_bounds__(256) void kA(
    const float* __restrict__ h, const float* __restrict__ W,
    const float* __restrict__ a, __bf16* __restrict__ whmH,
    __bf16* __restrict__ whmL, float* __restrict__ fo, float* __restrict__ go)
{
    __shared__ __bf16 wmfH[8192];       // [c][T][lane*8+idx] B-frag hi (16 KB)
    __shared__ __bf16 wmfL[8192];       // lo residual (16 KB)
    __shared__ float  wfl[INF], wgl[INF]; // prescaled by LOG2E
    __shared__ float  al[2 * OHH];

    const int t    = threadIdx.x;
    const int lane = t & 63;
    const int w    = t >> 6;
    const int R0   = blockIdx.x * 64;   // never straddles a batch (64 | 1024)

    // stage a
    al[t]       = a[t];
    al[t + 256] = a[t + 256];

    // WM in B-frag layout, hi/lo split (RNE): 2048 float4-groups
    for (int g = t; g < 2048; g += 256) {
        const int k  = g >> 4;
        const int n0 = (g & 15) << 2;
        const float* Wp = W + k * OHH + n0;
        float4 w0 = *(const float4*)Wp;
        float4 w1 = *(const float4*)(Wp + 64);
        float4 w2 = *(const float4*)(Wp + 128);
        float4 w3 = *(const float4*)(Wp + 192);
        float wm4[4] = {0.25f * (w0.x + w1.x + w2.x + w3.x),
                        0.25f * (w0.y + w1.y + w2.y + w3.y),
                        0.25f * (w0.z + w1.z + w2.z + w3.z),
                        0.25f * (w0.w + w1.w + w2.w + w3.w)};
        const int c = k >> 5, kq = (k >> 3) & 3, id8 = k & 7, T = n0 >> 4;
        const int lbase = kq * 16 + (n0 & 15);
        #pragma unroll
        for (int j = 0; j < 4; ++j) {
            float  v  = wm4[j];
            __bf16 hb = (__bf16)v;                 // RNE hi
            const int o = ((c * 4 + T) * 64 + lbase + j) * 8 + id8;
            wmfH[o] = hb;
            wmfL[o] = (__bf16)(v - (float)hb);     // residual
        }
    }
    __syncthreads();   // al + wmf ready

    // w_f (t<128) / w_g (t>=128): one 256-dot each; W rows L1/L2-hot
    {
        const int row = t & 127;
        const float4* Wr = (const float4*)(W + row * OHH);
        const float4* av = (const float4*)(t < 128 ? al : al + OHH);
        float s = 0.f;
        for (int q = 0; q < OHH / 4; ++q) {
            float4 wv = Wr[q], x = av[q];
            s += wv.x * x.x + wv.y * x.y + wv.z * x.z + wv.w * x.w;
        }
        if (t < 128) wfl[row] = s * LOG2E;
        else         wgl[row] = s * LOG2E;
    }
    __syncthreads();   // wfl/wgl ready

    // main: A-frag rows direct from global, 3-term split MFMA
    const int m  = lane & 15;
    const int kq = lane >> 4;
    const float* hrow = h + (size_t)(R0 + w * 16 + m) * INF + kq * 8;

    f32x4 acc[4] = {};
    float sf = 0.f, sg = 0.f;

    #pragma unroll
    for (int c = 0; c < 4; ++c) {
        float4 v0 = *(const float4*)(hrow + c * 32);
        float4 v1 = *(const float4*)(hrow + c * 32 + 4);
        float hv[8] = {v0.x, v0.y, v0.z, v0.w, v1.x, v1.y, v1.z, v1.w};

        float4 wf0 = *(const float4*)(wfl + c * 32 + kq * 8);
        float4 wf1 = *(const float4*)(wfl + c * 32 + kq * 8 + 4);
        float4 wg0 = *(const float4*)(wgl + c * 32 + kq * 8);
        float4 wg1 = *(const float4*)(wgl + c * 32 + kq * 8 + 4);
        float wfv[8] = {wf0.x, wf0.y, wf0.z, wf0.w, wf1.x, wf1.y, wf1.z, wf1.w};
        float wgv[8] = {wg0.x, wg0.y, wg0.z, wg0.w, wg1.x, wg1.y, wg1.z, wg1.w};

        u16x8  ahu;
        bf16x8 alo;
        #pragma unroll
        for (int i = 0; i < 8; ++i) {
            float v = hv[i];
            sf = fmaf(v, wfv[i], sf);
            sg = fmaf(v, wgv[i], sg);
            unsigned u = __float_as_uint(v);
            ahu[i] = (unsigned short)(u >> 16);                      // trunc hi
            alo[i] = (__bf16)(v - __uint_as_float(u & 0xFFFF0000u)); // exact resid
        }
        bf16x8 ah = __builtin_bit_cast(bf16x8, ahu);

        #pragma unroll
        for (int T = 0; T < 4; ++T) {
            bf16x8 bh = *(const bf16x8*)&wmfH[((c * 4 + T) * 64 + lane) * 8];
            bf16x8 bl = *(const bf16x8*)&wmfL[((c * 4 + T) * 64 + lane) * 8];
            acc[T] = __builtin_amdgcn_mfma_f32_16x16x32_bf16(ah,  bh, acc[T], 0, 0, 0);
            acc[T] = __builtin_amdgcn_mfma_f32_16x16x32_bf16(alo, bh, acc[T], 0, 0, 0);
            acc[T] = __builtin_amdgcn_mfma_f32_16x16x32_bf16(ah,  bl, acc[T], 0, 0, 0);
        }
    }

    // f,g: sum the 4 k-strips (lanes m, m+16, m+32, m+48)
    sf += __shfl_xor(sf, 16, 64); sf += __shfl_xor(sf, 32, 64);
    sg += __shfl_xor(sg, 16, 64); sg += __shfl_xor(sg, 32, 64);
    if (lane < 16) {
        fo[R0 + w * 16 + m] = sf;
        go[R0 + w * 16 + m] = sg;
    }

    // epilogue: C/D (row = kq*4+r, col = m) -> B-frag flat store, hi/lo split
    {
        const int n     = R0 >> 10;
        const int Jb    = ((R0 & 1023) >> 5) + (w >> 1);
        const int jj3   = 2 * (w & 1) + (kq >> 1);  // (j&31)>>3, r-invariant
        const int laneS = jj3 * 16 + m;
        const int idx0  = (kq & 1) * 4;             // idx' = 4*(kq&1)+r
        #pragma unroll
        for (int T = 0; T < 4; ++T) {
            const size_t base =
                (((size_t)(n * 32 + Jb) * 4 + T) * 64 + laneS) * 8 + idx0;
            bf16x4 hv, lv;
            #pragma unroll
            for (int r = 0; r < 4; ++r) {
                float  v  = acc[T][r];
                __bf16 hb = (__bf16)v;               // RNE hi
                hv[r] = hb;
                lv[r] = (__bf16)(v - (float)hb);     // exact residual
            }
            *(bf16x4*)(whmH + base) = hv;
            *(bf16x4*)(whmL + base) = lv;
        }
    }
}

// ---------------------------------------------------------------------------
// Kernel C: per (batch n, 64-row i-tile): out = softmax_j(lrelu(f_i+g_j)) @ WhM
// split-bf16 MFMA 16x16x32, 3-deep async LDS ring (global_load_lds dwordx4),
// one __syncthreads per J. P-gen in log2 domain with truncation split.
// ---------------------------------------------------------------------------
__global__ __launch_bounds__(256) void kC(
    const __bf16* __restrict__ whmH, const __bf16* __restrict__ whmL,
    const float* __restrict__ fi, const float* __restrict__ gi,
    float* __restrict__ out)
{
    __shared__ float  gl[SQ];
    __shared__ float  fl[64];
    __shared__ __bf16 bfr[3][4096];  // ring: 3 x (hi 4KB + lo 4KB)

    const int t     = threadIdx.x;
    const int lane  = t & 63;
    const int wid   = t >> 6;
    const int n     = blockIdx.x & 31;   // bx%8 == n%8 -> batch pinned per XCD
    const int itile = blockIdx.x >> 5;
    const int i0    = itile * 64;

    const char* gHb = (const char*)(whmH + (size_t)n * 65536) + wid * 1024 + lane * 16;
    const char* gLb = (const char*)(whmL + (size_t)n * 65536) + wid * 1024 + lane * 16;

    auto stage = [&](int J, int buf) {
        char* lH = (char*)&bfr[buf][0] + wid * 1024;          // wave-uniform base
        char* lL = (char*)&bfr[buf][2048] + wid * 1024;
        __builtin_amdgcn_global_load_lds(
            (const __attribute__((address_space(1))) unsigned int*)(gHb + (size_t)J * 4096),
            (__attribute__((address_space(3))) unsigned int*)lH, 16, 0, 0);
        __builtin_amdgcn_global_load_lds(
            (const __attribute__((address_space(1))) unsigned int*)(gLb + (size_t)J * 4096),
            (__attribute__((address_space(3))) unsigned int*)lL, 16, 0, 0);
    };

    // stage g' (4KB) and f' (64 rows)  [already scaled by log2e in kA]
    ((float4*)gl)[t] = ((const float4*)(gi + n * SQ))[t];
    if (t < 64) fl[t] = fi[n * SQ + i0 + t];

    stage(0, 0);
    stage(1, 1);
    __syncthreads();

    const float myf = fl[wid * 16 + (lane & 15)]; // A-frag row m = lane&15
    const int   kq  = lane >> 4;                  // A-frag k-quad

    f32x4 acc[4] = {};
    float lsum = 0.f;

    for (int J = 0; J < 32; ++J) {
        // P-gen (reads only gl/fl) — overlaps other waves' MFMA
        float4 g0 = *(const float4*)&gl[J * 32 + kq * 8];
        float4 g1 = *(const float4*)&gl[J * 32 + kq * 8 + 4];
        float gs8[8] = {g0.x, g0.y, g0.z, g0.w, g1.x, g1.y, g1.z, g1.w};

        u16x8  phu;
        bf16x8 pl;
        #pragma unroll
        for (int idx = 0; idx < 8; ++idx) {
            float e  = myf + gs8[idx];
            float lr = fmaxf(e, 0.1f * e);            // lrelu (log2 domain)
            float p  = EXP2F(lr);                     // fp32-range safe
            lsum += p;
            unsigned u = __float_as_uint(p);
            phu[idx] = (unsigned short)(u >> 16);     // trunc hi
            pl[idx]  = (__bf16)(p - __uint_as_float(u & 0xFFFF0000u));
        }
        bf16x8 ph = __builtin_bit_cast(bf16x8, phu);

        // barrier: all waves done MFMA(J-1); vmcnt drain completes stage(J)
        __syncthreads();
        if (J + 2 < 32) stage(J + 2, (J + 2) % 3);    // in flight during MFMA(J)

        const bf16x8* fr = (const bf16x8*)&bfr[J % 3][0];
        #pragma unroll
        for (int T = 0; T < 4; ++T) {
            bf16x8 bh = fr[T * 64 + lane];
            bf16x8 bl = fr[(4 + T) * 64 + lane];
            acc[T] = __builtin_amdgcn_mfma_f32_16x16x32_bf16(ph, bh, acc[T], 0, 0, 0);
            acc[T] = __builtin_amdgcn_mfma_f32_16x16x32_bf16(pl, bh, acc[T], 0, 0, 0);
            acc[T] = __builtin_amdgcn_mfma_f32_16x16x32_bf16(ph, bl, acc[T], 0, 0, 0);
        }
    }

    // l reduction: row m lives in lanes {m, m+16, m+32, m+48}
    lsum += __shfl_xor(lsum, 16, 64);
    lsum += __shfl_xor(lsum, 32, 64);
    const float rv = 1.0f / lsum;

    const int rq = lane >> 4;
    float scs[4];
    #pragma unroll
    for (int r = 0; r < 4; ++r)
        scs[r] = __shfl(rv, rq * 4 + r, 64);  // C/D row = rq*4 + reg

    const int colbase = lane & 15;
    #pragma unroll
    for (int T = 0; T < 4; ++T) {
        #pragma unroll
        for (int r = 0; r < 4; ++r) {
            int   rr = rq * 4 + r;
            float v  = acc[T][r] * scs[r];
            v = v > 0.f ? v : expm1f(v);      // final ELU
            out[(size_t)(n * SQ + i0 + wid * 16 + rr) * OUTF + T * 16 + colbase] = v;
        }
    }
}

extern "C" void kernel_launch(void* const* d_in, const int* in_sizes, int n_in,
                              void* d_out, int out_size, void* d_ws, size_t ws_size,
                              hipStream_t stream) {
    const float* h = (const float*)d_in[0];
    // d_in[1] = adj : unused by the reference computation
    const float* W = (const float*)d_in[2];
    const float* a = (const float*)d_in[3];

    char* ws = (char*)d_ws;
    __bf16* whmH = (__bf16*)ws;                                   // 4 MB
    __bf16* whmL = (__bf16*)(ws + (size_t)4 * 1024 * 1024);       // 4 MB
    float*  fb   = (float*)(ws + (size_t)8 * 1024 * 1024);        // 128 KB
    float*  gb   = (float*)(ws + (size_t)8 * 1024 * 1024 + 131072);
    float*  outp = (float*)d_out;

    hipLaunchKernelGGL(kA, dim3(512), dim3(256), 0, stream, h, W, a, whmH, whmL, fb, gb);
    hipLaunchKernelGGL(kC, dim3(512), dim3(256), 0, stream, whmH, whmL, fb, gb, outp);
}